// Round 2
// baseline (2022.808 us; speedup 1.0000x reference)
//
#include <hip/hip_runtime.h>
#include <hip/hip_bf16.h>
#include <math.h>

#define NLAYER 4
#define NBATCH 2
#define LWORD 1024
#define LENT 64
#define SEQ 1088
#define HID 768
#define NHEAD 12
#define DHEAD 64
#define FFDIM 3072

typedef __bf16 bf16_t;
typedef __bf16 bf16x8 __attribute__((ext_vector_type(8)));
typedef float f32x4 __attribute__((ext_vector_type(4)));

__device__ __forceinline__ bf16_t f2bf(float x) { return (bf16_t)x; }

// swizzle for 64B rows (4 x 16B chunks): 2-way max conflict
#define SWZ4(r, c) (((c) ^ ((r) & 3) ^ (((r) >> 2) & 3)) << 4)
// swizzle for 128B rows (8 x 16B chunks)
#define SWZ8(r, c) (((c) ^ ((r) & 7)) << 4)

// ---------- weight transpose + convert: dst[l][roff+n][k] = src[l][k][n] ----------
__global__ __launch_bounds__(256) void wconv_kernel(
    const float* __restrict__ src, bf16_t* __restrict__ dst,
    int K, int N, int roff, int Rtot)
{
  int n0 = blockIdx.x * 64, k0 = blockIdx.y * 64, l = blockIdx.z;
  src += (size_t)l * K * N;
  dst += (size_t)l * Rtot * K;
  __shared__ float tile[64][65];
  int tid = threadIdx.x;
#pragma unroll
  for (int j = 0; j < 16; j++) {
    int e = j * 256 + tid;
    int rr = e >> 6, cc = e & 63;
    tile[rr][cc] = src[(size_t)(k0 + rr) * N + n0 + cc];
  }
  __syncthreads();
#pragma unroll
  for (int j = 0; j < 16; j++) {
    int e = j * 256 + tid;
    int rr = e >> 6, cc = e & 63; // rr = n index, cc = k index
    dst[(size_t)(roff + n0 + rr) * K + k0 + cc] = f2bf(tile[cc][rr]);
  }
}

// ---------- concat word+entity -> h (fp32 + bf16) ----------
__global__ __launch_bounds__(256) void concat_kernel(
    const float* __restrict__ wh, const float* __restrict__ eh,
    float* __restrict__ hf, bf16_t* __restrict__ hb)
{
  size_t i = (size_t)blockIdx.x * 256 + threadIdx.x;
  if (i >= (size_t)NBATCH * SEQ * HID) return;
  int c = (int)(i % HID);
  size_t t = i / HID;
  int s = (int)(t % SEQ);
  int b = (int)(t / SEQ);
  float v = (s < LWORD) ? wh[((size_t)b * LWORD + s) * HID + c]
                        : eh[((size_t)b * LENT + (s - LWORD)) * HID + c];
  hf[i] = v;
  hb[i] = f2bf(v);
}

// ---------- bf16 MFMA GEMM: C = A(M,K) @ Wt(N,K)^T + bias ----------
// mode 0: fp32 out; mode 1: bf16 out; mode 2: exact-GELU bf16 out
__global__ __launch_bounds__(256) void gemm_bf16(
    const bf16_t* __restrict__ A, int lda, long aStride,
    const bf16_t* __restrict__ Wt,
    const float* __restrict__ bias0, const float* __restrict__ bias1, int nsplit,
    float* __restrict__ Cf, bf16_t* __restrict__ Cb, int ldc, long cStride,
    int M, int N, int K, int mode)
{
  const int tid = threadIdx.x, lane = tid & 63, wid = tid >> 6;
  const int wm = wid >> 1, wn = wid & 1;
  const int m0 = blockIdx.y * 128, n0 = blockIdx.x * 128;
  const int z = blockIdx.z;
  const int g = lane >> 4, qq = lane & 15;
  A += (size_t)z * aStride;
  __shared__ char As[8192];
  __shared__ char Bs[8192];

  f32x4 acc[4][4] = {};
  uint4 ra[2], rb[2];

  auto ldglobal = [&](int k0) {
#pragma unroll
    for (int j = 0; j < 2; j++) {
      int o = j * 4096 + tid * 16;
      int r = o >> 6, cb = o & 63;
      int ar = m0 + r; ar = (ar < M) ? ar : (M - 1);
      ra[j] = *(const uint4*)((const char*)(A + (size_t)ar * lda + k0) + cb);
      rb[j] = *(const uint4*)((const char*)(Wt + (size_t)(n0 + r) * K + k0) + cb);
    }
  };
  auto st_lds = [&]() {
#pragma unroll
    for (int j = 0; j < 2; j++) {
      int o = j * 4096 + tid * 16;
      int r = o >> 6, c = (o >> 4) & 3;
      int sw = r * 64 + SWZ4(r, c);
      *(uint4*)(As + sw) = ra[j];
      *(uint4*)(Bs + sw) = rb[j];
    }
  };

  ldglobal(0);
  for (int k0 = 0; k0 < K; k0 += 32) {
    __syncthreads();
    st_lds();
    __syncthreads();
    if (k0 + 32 < K) ldglobal(k0 + 32);
    bf16x8 af[4], bfr[4];
#pragma unroll
    for (int mi = 0; mi < 4; mi++) {
      int r = wm * 64 + mi * 16 + qq;
      af[mi] = *(const bf16x8*)(As + r * 64 + SWZ4(r, g));
    }
#pragma unroll
    for (int ni = 0; ni < 4; ni++) {
      int r = wn * 64 + ni * 16 + qq;
      bfr[ni] = *(const bf16x8*)(Bs + r * 64 + SWZ4(r, g));
    }
#pragma unroll
    for (int mi = 0; mi < 4; mi++)
#pragma unroll
      for (int ni = 0; ni < 4; ni++)
        acc[mi][ni] = __builtin_amdgcn_mfma_f32_16x16x32_bf16(af[mi], bfr[ni], acc[mi][ni], 0, 0, 0);
  }

#pragma unroll
  for (int mi = 0; mi < 4; mi++) {
#pragma unroll
    for (int ni = 0; ni < 4; ni++) {
      int col = n0 + wn * 64 + ni * 16 + qq;
      float bv = (col < nsplit) ? bias0[col] : bias1[col - nsplit];
#pragma unroll
      for (int e = 0; e < 4; e++) {
        int r = m0 + wm * 64 + mi * 16 + g * 4 + e;
        if (r < M) {
          float x = acc[mi][ni][e] + bv;
          size_t off = (size_t)z * cStride + (size_t)r * ldc + col;
          if (mode == 0) Cf[off] = x;
          else if (mode == 1) Cb[off] = f2bf(x);
          else {
            float xg = 0.5f * x * (1.0f + erff(x * 0.70710678118654752f));
            Cb[off] = f2bf(xg);
          }
        }
      }
    }
  }
}

// ---------- transpose V (from KV cols 768..1535) -> Vt (B,NH,DH,SEQ) ----------
__global__ __launch_bounds__(256) void vtrans_kernel(
    const bf16_t* __restrict__ KV, bf16_t* __restrict__ Vt)
{
  int kt = blockIdx.x, head = blockIdx.y, b = blockIdx.z;
  __shared__ bf16_t tile[64][65];
  int tid = threadIdx.x;
#pragma unroll
  for (int j = 0; j < 16; j++) {
    int e = j * 256 + tid;
    int rr = e >> 6, cc = e & 63; // rr = key, cc = dh
    tile[rr][cc] = KV[((size_t)(b * SEQ + kt * 64 + rr)) * 1536 + 768 + head * 64 + cc];
  }
  __syncthreads();
#pragma unroll
  for (int j = 0; j < 16; j++) {
    int e = j * 256 + tid;
    int rr = e >> 6, cc = e & 63; // rr = dh, cc = key
    Vt[(((size_t)(b * NHEAD + head)) * 64 + rr) * SEQ + kt * 64 + cc] = tile[cc][rr];
  }
}

// ---------- flash attention: scores = Q1/Q2 . K^T, online softmax, ctx = P V ----------
__global__ __launch_bounds__(256) void attn_kernel(
    const bf16_t* __restrict__ KV, const bf16_t* __restrict__ Q12,
    const bf16_t* __restrict__ Vt, const float* __restrict__ mask,
    bf16_t* __restrict__ ctx)
{
  const int tid = threadIdx.x, lane = tid & 63, w = tid >> 6;
  const int qt = blockIdx.x, head = blockIdx.y, b = blockIdx.z;
  const int g = lane >> 4, qq = lane & 15;
  const int q0 = qt * 64 + w * 16;
  __shared__ char Ks[8192];
  __shared__ char Vs[8192];
  __shared__ bf16_t Pl[4][16][32];

  bf16x8 q1f[2], q2f[2];
  {
    const bf16_t* Qb = Q12 + ((size_t)(b * SEQ + q0 + qq)) * 1536 + head * 64;
#pragma unroll
    for (int kk = 0; kk < 2; kk++) {
      q1f[kk] = *(const bf16x8*)(Qb + kk * 32 + g * 8);
      q2f[kk] = *(const bf16x8*)(Qb + 768 + kk * 32 + g * 8);
    }
  }

  f32x4 oacc[4] = {};
  float mrun[4] = {-INFINITY, -INFINITY, -INFINITY, -INFINITY};
  float lrun[4] = {0.f, 0.f, 0.f, 0.f};

  for (int t = 0; t < SEQ / 64; t++) {
    int key0 = t * 64;
    __syncthreads();
#pragma unroll
    for (int j = 0; j < 2; j++) {
      int o = j * 4096 + tid * 16;
      int r = o >> 7, c = (o >> 4) & 7;
      int sw = r * 128 + SWZ8(r, c);
      uint4 vk = *(const uint4*)(KV + (size_t)(b * SEQ + key0 + r) * 1536 + head * 64 + c * 8);
      *(uint4*)(Ks + sw) = vk;
      uint4 vv = *(const uint4*)(Vt + ((size_t)(b * NHEAD + head) * 64 + r) * SEQ + key0 + c * 8);
      *(uint4*)(Vs + sw) = vv;
    }
    __syncthreads();
    const bool useQ2 = (key0 >= LWORD);
#pragma unroll
    for (int ch = 0; ch < 2; ch++) {
      f32x4 s0 = {}, s1 = {};
#pragma unroll
      for (int kk = 0; kk < 2; kk++) {
        int r0 = ch * 32 + qq, r1 = r0 + 16;
        int c = kk * 4 + g;
        bf16x8 kf0 = *(const bf16x8*)(Ks + r0 * 128 + SWZ8(r0, c));
        bf16x8 kf1 = *(const bf16x8*)(Ks + r1 * 128 + SWZ8(r1, c));
        bf16x8 qf = useQ2 ? q2f[kk] : q1f[kk];
        s0 = __builtin_amdgcn_mfma_f32_16x16x32_bf16(qf, kf0, s0, 0, 0, 0);
        s1 = __builtin_amdgcn_mfma_f32_16x16x32_bf16(qf, kf1, s1, 0, 0, 0);
      }
      float mk0 = mask[b * SEQ + key0 + ch * 32 + qq];
      float mk1 = mask[b * SEQ + key0 + ch * 32 + 16 + qq];
      f32x4 mx;
#pragma unroll
      for (int e = 0; e < 4; e++) {
        s0[e] = s0[e] * 0.125f + mk0;
        s1[e] = s1[e] * 0.125f + mk1;
        mx[e] = fmaxf(s0[e], s1[e]);
      }
#pragma unroll
      for (int d = 1; d < 16; d <<= 1)
#pragma unroll
        for (int e = 0; e < 4; e++) mx[e] = fmaxf(mx[e], __shfl_xor(mx[e], d));
      float corr[4];
#pragma unroll
      for (int e = 0; e < 4; e++) {
        float mnew = fmaxf(mrun[e], mx[e]);
        corr[e] = __expf(mrun[e] - mnew);
        mrun[e] = mnew;
        lrun[e] *= corr[e];
      }
#pragma unroll
      for (int f = 0; f < 4; f++)
#pragma unroll
        for (int e = 0; e < 4; e++) oacc[f][e] *= corr[e];
      f32x4 p0, p1, rs;
#pragma unroll
      for (int e = 0; e < 4; e++) {
        p0[e] = __expf(s0[e] - mrun[e]);
        p1[e] = __expf(s1[e] - mrun[e]);
        rs[e] = p0[e] + p1[e];
      }
#pragma unroll
      for (int d = 1; d < 16; d <<= 1)
#pragma unroll
        for (int e = 0; e < 4; e++) rs[e] += __shfl_xor(rs[e], d);
#pragma unroll
      for (int e = 0; e < 4; e++) {
        lrun[e] += rs[e];
        Pl[w][g * 4 + e][qq] = f2bf(p0[e]);
        Pl[w][g * 4 + e][16 + qq] = f2bf(p1[e]);
      }
      bf16x8 pf = *(const bf16x8*)(&Pl[w][qq][g * 8]);
#pragma unroll
      for (int f = 0; f < 4; f++) {
        int r = f * 16 + qq;
        int c = ch * 4 + g;
        bf16x8 vf = *(const bf16x8*)(Vs + r * 128 + SWZ8(r, c));
        oacc[f] = __builtin_amdgcn_mfma_f32_16x16x32_bf16(pf, vf, oacc[f], 0, 0, 0);
      }
    }
  }
#pragma unroll
  for (int f = 0; f < 4; f++)
#pragma unroll
    for (int e = 0; e < 4; e++) {
      float val = oacc[f][e] / lrun[e];
      int row = q0 + g * 4 + e;
      ctx[((size_t)(b * SEQ) + row) * HID + head * 64 + f * 16 + qq] = f2bf(val);
    }
}

// ---------- residual + LayerNorm -> fp32 out + bf16 out ----------
__global__ __launch_bounds__(256) void ln_kernel(
    const float* __restrict__ X, const float* __restrict__ R,
    const float* __restrict__ gamma, const float* __restrict__ beta,
    float* __restrict__ outF, bf16_t* __restrict__ outB)
{
  int row = blockIdx.x;
  const float* x = X + (size_t)row * HID;
  const float* r = R + (size_t)row * HID;
  int tid = threadIdx.x;
  float v[3];
  float s = 0.f, ss = 0.f;
#pragma unroll
  for (int j = 0; j < 3; j++) {
    int c = tid + j * 256;
    float t = x[c] + r[c];
    v[j] = t; s += t; ss += t * t;
  }
#pragma unroll
  for (int d = 1; d < 64; d <<= 1) { s += __shfl_xor(s, d); ss += __shfl_xor(ss, d); }
  __shared__ float red[8];
  int wid = tid >> 6, lane = tid & 63;
  if (lane == 0) { red[wid] = s; red[4 + wid] = ss; }
  __syncthreads();
  s = red[0] + red[1] + red[2] + red[3];
  ss = red[4] + red[5] + red[6] + red[7];
  float mean = s * (1.0f / HID);
  float var = ss * (1.0f / HID) - mean * mean;
  float inv = rsqrtf(var + 1e-12f);
#pragma unroll
  for (int j = 0; j < 3; j++) {
    int c = tid + j * 256;
    float y = (v[j] - mean) * inv * gamma[c] + beta[c];
    outF[(size_t)row * HID + c] = y;
    outB[(size_t)row * HID + c] = f2bf(y);
  }
}

extern "C" void kernel_launch(void* const* d_in, const int* in_sizes, int n_in,
                              void* d_out, int out_size, void* d_ws, size_t ws_size,
                              hipStream_t stream) {
  (void)in_sizes; (void)n_in; (void)out_size; (void)ws_size;
  const float* wh     = (const float*)d_in[0];
  const float* ehs    = (const float*)d_in[1];
  const float* mask   = (const float*)d_in[2];
  const float* Wq     = (const float*)d_in[3];  const float* bq     = (const float*)d_in[4];
  const float* Wk     = (const float*)d_in[5];  const float* bk     = (const float*)d_in[6];
  const float* Wv     = (const float*)d_in[7];  const float* bv     = (const float*)d_in[8];
  const float* Wq_w2e = (const float*)d_in[9];  const float* bq_w2e = (const float*)d_in[10];
  const float* Wq_e2w = (const float*)d_in[11]; const float* bq_e2w = (const float*)d_in[12];
  const float* Wq_e2e = (const float*)d_in[13]; const float* bq_e2e = (const float*)d_in[14];
  const float* Wo     = (const float*)d_in[15]; const float* bo     = (const float*)d_in[16];
  const float* Wi     = (const float*)d_in[17]; const float* bi     = (const float*)d_in[18];
  const float* Wo2    = (const float*)d_in[19]; const float* bo2    = (const float*)d_in[20];
  const float* g1     = (const float*)d_in[21]; const float* b1     = (const float*)d_in[22];
  const float* g2     = (const float*)d_in[23]; const float* b2     = (const float*)d_in[24];
  float* out = (float*)d_out;

  const size_t BSH = (size_t)NBATCH * SEQ * HID;
  char* ws = (char*)d_ws;
  size_t off = 0;
  auto alloc = [&](size_t bytes) -> char* {
    char* p = ws + off; off += (bytes + 255) & ~(size_t)255; return p;
  };
  bf16_t* WkvT  = (bf16_t*)alloc((size_t)NLAYER * 1536 * HID * 2);
  bf16_t* Wq1wT = (bf16_t*)alloc((size_t)NLAYER * 1536 * HID * 2);
  bf16_t* Wq1eT = (bf16_t*)alloc((size_t)NLAYER * 1536 * HID * 2);
  bf16_t* WoT   = (bf16_t*)alloc((size_t)NLAYER * HID * HID * 2);
  bf16_t* WiT   = (bf16_t*)alloc((size_t)NLAYER * FFDIM * HID * 2);
  bf16_t* Wo2T  = (bf16_t*)alloc((size_t)NLAYER * HID * FFDIM * 2);
  float*  h0f   = (float*) alloc(BSH * 4);
  bf16_t* hb    = (bf16_t*)alloc(BSH * 2);
  bf16_t* KVb   = (bf16_t*)alloc((size_t)NBATCH * SEQ * 1536 * 2);
  bf16_t* Q12   = (bf16_t*)alloc((size_t)NBATCH * SEQ * 1536 * 2);
  bf16_t* Vt    = (bf16_t*)alloc((size_t)NBATCH * NHEAD * DHEAD * SEQ * 2);
  bf16_t* ctxb  = (bf16_t*)alloc(BSH * 2);
  float*  tmpf  = (float*) alloc(BSH * 4);
  float*  attnf = (float*) alloc(BSH * 4);
  bf16_t* attnb = (bf16_t*)alloc(BSH * 2);
  bf16_t* interb= (bf16_t*)alloc((size_t)NBATCH * SEQ * FFDIM * 2);

  // one-time per call: weight convert+transpose, input concat
  wconv_kernel<<<dim3(12, 12, 4), 256, 0, stream>>>(Wk, WkvT, HID, HID, 0, 1536);
  wconv_kernel<<<dim3(12, 12, 4), 256, 0, stream>>>(Wv, WkvT, HID, HID, 768, 1536);
  wconv_kernel<<<dim3(12, 12, 4), 256, 0, stream>>>(Wq, Wq1wT, HID, HID, 0, 1536);
  wconv_kernel<<<dim3(12, 12, 4), 256, 0, stream>>>(Wq_w2e, Wq1wT, HID, HID, 768, 1536);
  wconv_kernel<<<dim3(12, 12, 4), 256, 0, stream>>>(Wq_e2w, Wq1eT, HID, HID, 0, 1536);
  wconv_kernel<<<dim3(12, 12, 4), 256, 0, stream>>>(Wq_e2e, Wq1eT, HID, HID, 768, 1536);
  wconv_kernel<<<dim3(12, 12, 4), 256, 0, stream>>>(Wo, WoT, HID, HID, 0, 768);
  wconv_kernel<<<dim3(48, 12, 4), 256, 0, stream>>>(Wi, WiT, HID, FFDIM, 0, 3072);
  wconv_kernel<<<dim3(12, 48, 4), 256, 0, stream>>>(Wo2, Wo2T, FFDIM, HID, 0, 768);
  concat_kernel<<<6528, 256, 0, stream>>>(wh, ehs, h0f, hb);

  for (int l = 0; l < NLAYER; l++) {
    const float* hf = (l == 0) ? h0f : (out + (size_t)(l - 1) * BSH);
    // K|V (N=1536)
    gemm_bf16<<<dim3(12, 17, 1), 256, 0, stream>>>(hb, HID, 0,
        WkvT + (size_t)l * 1536 * HID, bk + l * HID, bv + l * HID, HID,
        nullptr, KVb, 1536, 0, NBATCH * SEQ, 1536, HID, 1);
    // Q1|Q2 for word rows (batched)
    gemm_bf16<<<dim3(12, 8, 2), 256, 0, stream>>>(hb, HID, (long)SEQ * HID,
        Wq1wT + (size_t)l * 1536 * HID, bq + l * HID, bq_w2e + l * HID, HID,
        nullptr, Q12, 1536, (long)SEQ * 1536, LWORD, 1536, HID, 1);
    // Q1|Q2 for entity rows (batched)
    gemm_bf16<<<dim3(12, 1, 2), 256, 0, stream>>>(hb + (size_t)LWORD * HID, HID, (long)SEQ * HID,
        Wq1eT + (size_t)l * 1536 * HID, bq_e2w + l * HID, bq_e2e + l * HID, HID,
        nullptr, Q12 + (size_t)LWORD * 1536, 1536, (long)SEQ * 1536, LENT, 1536, HID, 1);
    vtrans_kernel<<<dim3(17, 12, 2), 256, 0, stream>>>(KVb, Vt);
    attn_kernel<<<dim3(17, 12, 2), 256, 0, stream>>>(KVb, Q12, Vt, mask, ctxb);
    // O projection (fp32 out)
    gemm_bf16<<<dim3(6, 17, 1), 256, 0, stream>>>(ctxb, HID, 0,
        WoT + (size_t)l * HID * HID, bo + l * HID, bo + l * HID, HID,
        tmpf, nullptr, HID, 0, NBATCH * SEQ, HID, HID, 0);
    ln_kernel<<<NBATCH * SEQ, 256, 0, stream>>>(tmpf, hf, g1 + l * HID, b1 + l * HID, attnf, attnb);
    // FFN up + exact GELU (bf16 out)
    gemm_bf16<<<dim3(24, 17, 1), 256, 0, stream>>>(attnb, HID, 0,
        WiT + (size_t)l * FFDIM * HID, bi + l * FFDIM, bi + l * FFDIM, FFDIM,
        nullptr, interb, FFDIM, 0, NBATCH * SEQ, FFDIM, HID, 2);
    // FFN down (fp32 out)
    gemm_bf16<<<dim3(6, 17, 1), 256, 0, stream>>>(interb, FFDIM, 0,
        Wo2T + (size_t)l * HID * FFDIM, bo2 + l * HID, bo2 + l * HID, HID,
        tmpf, nullptr, HID, 0, NBATCH * SEQ, HID, FFDIM, 0);
    ln_kernel<<<NBATCH * SEQ, 256, 0, stream>>>(tmpf, attnf, g2 + l * HID, b2 + l * HID,
        out + (size_t)l * BSH, hb);
  }
}

// Round 3
// 1820.384 us; speedup vs baseline: 1.1112x; 1.1112x over previous
//
#include <hip/hip_runtime.h>
#include <hip/hip_bf16.h>
#include <math.h>

#define NLAYER 4
#define NBATCH 2
#define LWORD 1024
#define LENT 64
#define SEQ 1088
#define HID 768
#define NHEAD 12
#define DHEAD 64
#define FFDIM 3072

typedef __bf16 bf16_t;
typedef __bf16 bf16x8 __attribute__((ext_vector_type(8)));
typedef float f32x4 __attribute__((ext_vector_type(4)));

__device__ __forceinline__ bf16_t f2bf(float x) { return (bf16_t)x; }

// swizzle for 128B rows (8 x 16B chunks): reads are <=2-way conflicts (free, m136)
#define SWZ8(r, c) (((c) ^ ((r) & 7)) << 4)

// ---------- weight transpose + convert: dst[l][roff+n][k] = src[l][k][n] ----------
__global__ __launch_bounds__(256) void wconv_kernel(
    const float* __restrict__ src, bf16_t* __restrict__ dst,
    int K, int N, int roff, int Rtot)
{
  int n0 = blockIdx.x * 64, k0 = blockIdx.y * 64, l = blockIdx.z;
  src += (size_t)l * K * N;
  dst += (size_t)l * Rtot * K;
  __shared__ float tile[64][65];
  int tid = threadIdx.x;
#pragma unroll
  for (int j = 0; j < 16; j++) {
    int e = j * 256 + tid;
    int rr = e >> 6, cc = e & 63;
    tile[rr][cc] = src[(size_t)(k0 + rr) * N + n0 + cc];
  }
  __syncthreads();
#pragma unroll
  for (int j = 0; j < 16; j++) {
    int e = j * 256 + tid;
    int rr = e >> 6, cc = e & 63; // rr = n index, cc = k index
    dst[(size_t)(roff + n0 + rr) * K + k0 + cc] = f2bf(tile[cc][rr]);
  }
}

// ---------- concat word+entity -> h (fp32 + bf16) ----------
__global__ __launch_bounds__(256) void concat_kernel(
    const float* __restrict__ wh, const float* __restrict__ eh,
    float* __restrict__ hf, bf16_t* __restrict__ hb)
{
  size_t i = (size_t)blockIdx.x * 256 + threadIdx.x;
  if (i >= (size_t)NBATCH * SEQ * HID) return;
  int c = (int)(i % HID);
  size_t t = i / HID;
  int s = (int)(t % SEQ);
  int b = (int)(t / SEQ);
  float v = (s < LWORD) ? wh[((size_t)b * LWORD + s) * HID + c]
                        : eh[((size_t)b * LENT + (s - LWORD)) * HID + c];
  hf[i] = v;
  hb[i] = f2bf(v);
}

// ---------- bf16 MFMA GEMM: C = A(M,K) @ Wt(N,K)^T + bias ----------
// tile 128(M) x 64(N), BK=64, 4 waves (2x2), per-wave 64x32 (acc 4x2)
// mode 0: fp32 out; mode 1: bf16 out; mode 2: exact-GELU bf16 out
// kchunks>1: split-K over blockIdx.z, C partial plane z at z*cStride (bias only z==0)
// kchunks==1: blockIdx.z = batch index (A += z*aStride, C += z*cStride)
__global__ __launch_bounds__(256) void gemm_bf16(
    const bf16_t* __restrict__ A, int lda, long aStride,
    const bf16_t* __restrict__ Wt,
    const float* __restrict__ bias0, const float* __restrict__ bias1, int nsplit,
    float* __restrict__ Cf, bf16_t* __restrict__ Cb, int ldc, long cStride,
    int M, int N, int K, int mode, int kchunks)
{
  const int tid = threadIdx.x, lane = tid & 63, wid = tid >> 6;
  const int wm = wid >> 1, wn = wid & 1;
  const int m0 = blockIdx.y * 128, n0 = blockIdx.x * 64;
  const int z = blockIdx.z;
  const int g = lane >> 4, qq = lane & 15;
  int kb = 0, kn = K;
  if (kchunks > 1) { kn = K / kchunks; kb = z * kn; }
  else { A += (size_t)z * aStride; }
  __shared__ char As[16384];
  __shared__ char Bs[8192];

  f32x4 acc[4][2] = {};
  uint4 ra[4], rb[2];

  auto ldglobal = [&](int k0) {
#pragma unroll
    for (int j = 0; j < 4; j++) {
      int o = j * 4096 + tid * 16;
      int r = o >> 7, cb = o & 127;
      int ar = m0 + r; ar = (ar < M) ? ar : (M - 1);
      ra[j] = *(const uint4*)((const char*)(A + (size_t)ar * lda + kb + k0) + cb);
    }
#pragma unroll
    for (int j = 0; j < 2; j++) {
      int o = j * 4096 + tid * 16;
      int r = o >> 7, cb = o & 127;
      rb[j] = *(const uint4*)((const char*)(Wt + (size_t)(n0 + r) * K + kb + k0) + cb);
    }
  };
  auto st_lds = [&]() {
#pragma unroll
    for (int j = 0; j < 4; j++) {
      int o = j * 4096 + tid * 16;
      int r = o >> 7, c = (o >> 4) & 7;
      *(uint4*)(As + r * 128 + SWZ8(r, c)) = ra[j];
    }
#pragma unroll
    for (int j = 0; j < 2; j++) {
      int o = j * 4096 + tid * 16;
      int r = o >> 7, c = (o >> 4) & 7;
      *(uint4*)(Bs + r * 128 + SWZ8(r, c)) = rb[j];
    }
  };

  ldglobal(0);
  for (int k0 = 0; k0 < kn; k0 += 64) {
    __syncthreads();
    st_lds();
    __syncthreads();
    if (k0 + 64 < kn) ldglobal(k0 + 64);
#pragma unroll
    for (int kk = 0; kk < 2; kk++) {
      bf16x8 af[4], bfr[2];
#pragma unroll
      for (int mi = 0; mi < 4; mi++) {
        int r = wm * 64 + mi * 16 + qq;
        af[mi] = *(const bf16x8*)(As + r * 128 + SWZ8(r, kk * 4 + g));
      }
#pragma unroll
      for (int ni = 0; ni < 2; ni++) {
        int r = wn * 32 + ni * 16 + qq;
        bfr[ni] = *(const bf16x8*)(Bs + r * 128 + SWZ8(r, kk * 4 + g));
      }
#pragma unroll
      for (int mi = 0; mi < 4; mi++)
#pragma unroll
        for (int ni = 0; ni < 2; ni++)
          acc[mi][ni] = __builtin_amdgcn_mfma_f32_16x16x32_bf16(af[mi], bfr[ni], acc[mi][ni], 0, 0, 0);
    }
  }

  const bool addb = (kchunks <= 1) || (z == 0);
#pragma unroll
  for (int mi = 0; mi < 4; mi++) {
#pragma unroll
    for (int ni = 0; ni < 2; ni++) {
      int col = n0 + wn * 32 + ni * 16 + qq;
      float bv = addb ? ((col < nsplit) ? bias0[col] : bias1[col - nsplit]) : 0.f;
#pragma unroll
      for (int e = 0; e < 4; e++) {
        int r = m0 + wm * 64 + mi * 16 + g * 4 + e;
        if (r < M) {
          float x = acc[mi][ni][e] + bv;
          size_t off = (size_t)z * cStride + (size_t)r * ldc + col;
          if (mode == 0) Cf[off] = x;
          else if (mode == 1) Cb[off] = f2bf(x);
          else {
            float xg = 0.5f * x * (1.0f + erff(x * 0.70710678118654752f));
            Cb[off] = f2bf(xg);
          }
        }
      }
    }
  }
}

// ---------- transpose V (from KV cols 768..1535) -> Vt (B,NH,DH,SEQ) ----------
__global__ __launch_bounds__(256) void vtrans_kernel(
    const bf16_t* __restrict__ KV, bf16_t* __restrict__ Vt)
{
  int kt = blockIdx.x, head = blockIdx.y, b = blockIdx.z;
  __shared__ bf16_t tile[64][65];
  int tid = threadIdx.x;
#pragma unroll
  for (int j = 0; j < 16; j++) {
    int e = j * 256 + tid;
    int rr = e >> 6, cc = e & 63; // rr = key, cc = dh
    tile[rr][cc] = KV[((size_t)(b * SEQ + kt * 64 + rr)) * 1536 + 768 + head * 64 + cc];
  }
  __syncthreads();
#pragma unroll
  for (int j = 0; j < 16; j++) {
    int e = j * 256 + tid;
    int rr = e >> 6, cc = e & 63; // rr = dh, cc = key
    Vt[(((size_t)(b * NHEAD + head)) * 64 + rr) * SEQ + kt * 64 + cc] = tile[cc][rr];
  }
}

// ---------- flash attention: scores = Q1/Q2 . K^T, online softmax, ctx = P V ----------
__global__ __launch_bounds__(256) void attn_kernel(
    const bf16_t* __restrict__ KV, const bf16_t* __restrict__ Q12,
    const bf16_t* __restrict__ Vt, const float* __restrict__ mask,
    bf16_t* __restrict__ ctx)
{
  const int tid = threadIdx.x, lane = tid & 63, w = tid >> 6;
  const int qt = blockIdx.x, head = blockIdx.y, b = blockIdx.z;
  const int g = lane >> 4, qq = lane & 15;
  const int q0 = qt * 64 + w * 16;
  __shared__ char Ks[8192];
  __shared__ char Vs[8192];
  __shared__ bf16_t Pl[4][16][32];

  bf16x8 q1f[2], q2f[2];
  {
    const bf16_t* Qb = Q12 + ((size_t)(b * SEQ + q0 + qq)) * 1536 + head * 64;
#pragma unroll
    for (int kk = 0; kk < 2; kk++) {
      q1f[kk] = *(const bf16x8*)(Qb + kk * 32 + g * 8);
      q2f[kk] = *(const bf16x8*)(Qb + 768 + kk * 32 + g * 8);
    }
  }

  f32x4 oacc[4] = {};
  float mrun[4] = {-INFINITY, -INFINITY, -INFINITY, -INFINITY};
  float lrun[4] = {0.f, 0.f, 0.f, 0.f};

  for (int t = 0; t < SEQ / 64; t++) {
    int key0 = t * 64;
    __syncthreads();
#pragma unroll
    for (int j = 0; j < 2; j++) {
      int o = j * 4096 + tid * 16;
      int r = o >> 7, c = (o >> 4) & 7;
      int sw = r * 128 + SWZ8(r, c);
      uint4 vk = *(const uint4*)(KV + (size_t)(b * SEQ + key0 + r) * 1536 + head * 64 + c * 8);
      *(uint4*)(Ks + sw) = vk;
      uint4 vv = *(const uint4*)(Vt + ((size_t)(b * NHEAD + head) * 64 + r) * SEQ + key0 + c * 8);
      *(uint4*)(Vs + sw) = vv;
    }
    __syncthreads();
    const bool useQ2 = (key0 >= LWORD);
#pragma unroll
    for (int ch = 0; ch < 2; ch++) {
      f32x4 s0 = {}, s1 = {};
#pragma unroll
      for (int kk = 0; kk < 2; kk++) {
        int r0 = ch * 32 + qq, r1 = r0 + 16;
        int c = kk * 4 + g;
        bf16x8 kf0 = *(const bf16x8*)(Ks + r0 * 128 + SWZ8(r0, c));
        bf16x8 kf1 = *(const bf16x8*)(Ks + r1 * 128 + SWZ8(r1, c));
        bf16x8 qf = useQ2 ? q2f[kk] : q1f[kk];
        s0 = __builtin_amdgcn_mfma_f32_16x16x32_bf16(qf, kf0, s0, 0, 0, 0);
        s1 = __builtin_amdgcn_mfma_f32_16x16x32_bf16(qf, kf1, s1, 0, 0, 0);
      }
      float mk0 = mask[b * SEQ + key0 + ch * 32 + qq];
      float mk1 = mask[b * SEQ + key0 + ch * 32 + 16 + qq];
      f32x4 mx;
#pragma unroll
      for (int e = 0; e < 4; e++) {
        s0[e] = s0[e] * 0.125f + mk0;
        s1[e] = s1[e] * 0.125f + mk1;
        mx[e] = fmaxf(s0[e], s1[e]);
      }
#pragma unroll
      for (int d = 1; d < 16; d <<= 1)
#pragma unroll
        for (int e = 0; e < 4; e++) mx[e] = fmaxf(mx[e], __shfl_xor(mx[e], d));
      float corr[4];
#pragma unroll
      for (int e = 0; e < 4; e++) {
        float mnew = fmaxf(mrun[e], mx[e]);
        corr[e] = __expf(mrun[e] - mnew);
        mrun[e] = mnew;
        lrun[e] *= corr[e];
      }
#pragma unroll
      for (int f = 0; f < 4; f++)
#pragma unroll
        for (int e = 0; e < 4; e++) oacc[f][e] *= corr[e];
      f32x4 p0, p1, rs;
#pragma unroll
      for (int e = 0; e < 4; e++) {
        p0[e] = __expf(s0[e] - mrun[e]);
        p1[e] = __expf(s1[e] - mrun[e]);
        rs[e] = p0[e] + p1[e];
      }
#pragma unroll
      for (int d = 1; d < 16; d <<= 1)
#pragma unroll
        for (int e = 0; e < 4; e++) rs[e] += __shfl_xor(rs[e], d);
#pragma unroll
      for (int e = 0; e < 4; e++) {
        lrun[e] += rs[e];
        Pl[w][g * 4 + e][qq] = f2bf(p0[e]);
        Pl[w][g * 4 + e][16 + qq] = f2bf(p1[e]);
      }
      bf16x8 pf = *(const bf16x8*)(&Pl[w][qq][g * 8]);
#pragma unroll
      for (int f = 0; f < 4; f++) {
        int r = f * 16 + qq;
        int c = ch * 4 + g;
        bf16x8 vf = *(const bf16x8*)(Vs + r * 128 + SWZ8(r, c));
        oacc[f] = __builtin_amdgcn_mfma_f32_16x16x32_bf16(pf, vf, oacc[f], 0, 0, 0);
      }
    }
  }
#pragma unroll
  for (int f = 0; f < 4; f++)
#pragma unroll
    for (int e = 0; e < 4; e++) {
      float val = oacc[f][e] / lrun[e];
      int row = q0 + g * 4 + e;
      ctx[((size_t)(b * SEQ) + row) * HID + head * 64 + f * 16 + qq] = f2bf(val);
    }
}

// ---------- residual + sum of 2 split-K partials + LayerNorm -> fp32 + bf16 ----------
__global__ __launch_bounds__(256) void ln_kernel(
    const float* __restrict__ X0, const float* __restrict__ X1,
    const float* __restrict__ R,
    const float* __restrict__ gamma, const float* __restrict__ beta,
    float* __restrict__ outF, bf16_t* __restrict__ outB)
{
  int row = blockIdx.x;
  const float* x0 = X0 + (size_t)row * HID;
  const float* x1 = X1 + (size_t)row * HID;
  const float* r = R + (size_t)row * HID;
  int tid = threadIdx.x;
  float v[3];
  float s = 0.f, ss = 0.f;
#pragma unroll
  for (int j = 0; j < 3; j++) {
    int c = tid + j * 256;
    float t = x0[c] + x1[c] + r[c];
    v[j] = t; s += t; ss += t * t;
  }
#pragma unroll
  for (int d = 1; d < 64; d <<= 1) { s += __shfl_xor(s, d); ss += __shfl_xor(ss, d); }
  __shared__ float red[8];
  int wid = tid >> 6, lane = tid & 63;
  if (lane == 0) { red[wid] = s; red[4 + wid] = ss; }
  __syncthreads();
  s = red[0] + red[1] + red[2] + red[3];
  ss = red[4] + red[5] + red[6] + red[7];
  float mean = s * (1.0f / HID);
  float var = ss * (1.0f / HID) - mean * mean;
  float inv = rsqrtf(var + 1e-12f);
#pragma unroll
  for (int j = 0; j < 3; j++) {
    int c = tid + j * 256;
    float y = (v[j] - mean) * inv * gamma[c] + beta[c];
    outF[(size_t)row * HID + c] = y;
    outB[(size_t)row * HID + c] = f2bf(y);
  }
}

extern "C" void kernel_launch(void* const* d_in, const int* in_sizes, int n_in,
                              void* d_out, int out_size, void* d_ws, size_t ws_size,
                              hipStream_t stream) {
  (void)in_sizes; (void)n_in; (void)out_size; (void)ws_size;
  const float* wh     = (const float*)d_in[0];
  const float* ehs    = (const float*)d_in[1];
  const float* mask   = (const float*)d_in[2];
  const float* Wq     = (const float*)d_in[3];  const float* bq     = (const float*)d_in[4];
  const float* Wk     = (const float*)d_in[5];  const float* bk     = (const float*)d_in[6];
  const float* Wv     = (const float*)d_in[7];  const float* bv     = (const float*)d_in[8];
  const float* Wq_w2e = (const float*)d_in[9];  const float* bq_w2e = (const float*)d_in[10];
  const float* Wq_e2w = (const float*)d_in[11]; const float* bq_e2w = (const float*)d_in[12];
  const float* Wq_e2e = (const float*)d_in[13]; const float* bq_e2e = (const float*)d_in[14];
  const float* Wo     = (const float*)d_in[15]; const float* bo     = (const float*)d_in[16];
  const float* Wi     = (const float*)d_in[17]; const float* bi     = (const float*)d_in[18];
  const float* Wo2    = (const float*)d_in[19]; const float* bo2    = (const float*)d_in[20];
  const float* g1     = (const float*)d_in[21]; const float* b1     = (const float*)d_in[22];
  const float* g2     = (const float*)d_in[23]; const float* b2     = (const float*)d_in[24];
  float* out = (float*)d_out;

  const size_t BSH = (size_t)NBATCH * SEQ * HID;
  char* ws = (char*)d_ws;
  size_t off = 0;
  auto alloc = [&](size_t bytes) -> char* {
    char* p = ws + off; off += (bytes + 255) & ~(size_t)255; return p;
  };
  bf16_t* WkvT  = (bf16_t*)alloc((size_t)NLAYER * 1536 * HID * 2);
  bf16_t* Wq1wT = (bf16_t*)alloc((size_t)NLAYER * 1536 * HID * 2);
  bf16_t* Wq1eT = (bf16_t*)alloc((size_t)NLAYER * 1536 * HID * 2);
  bf16_t* WoT   = (bf16_t*)alloc((size_t)NLAYER * HID * HID * 2);
  bf16_t* WiT   = (bf16_t*)alloc((size_t)NLAYER * FFDIM * HID * 2);
  bf16_t* Wo2T  = (bf16_t*)alloc((size_t)NLAYER * HID * FFDIM * 2);
  float*  h0f   = (float*) alloc(BSH * 4);
  bf16_t* hb    = (bf16_t*)alloc(BSH * 2);
  bf16_t* KVb   = (bf16_t*)alloc((size_t)NBATCH * SEQ * 1536 * 2);
  bf16_t* Q12   = (bf16_t*)alloc((size_t)NBATCH * SEQ * 1536 * 2);
  bf16_t* Vt    = (bf16_t*)alloc((size_t)NBATCH * NHEAD * DHEAD * SEQ * 2);
  bf16_t* ctxb  = (bf16_t*)alloc(BSH * 2);
  float*  tmpf  = (float*) alloc(BSH * 4 * 2);   // 2 split-K partial planes
  float*  attnf = (float*) alloc(BSH * 4);
  bf16_t* attnb = (bf16_t*)alloc(BSH * 2);
  bf16_t* interb= (bf16_t*)alloc((size_t)NBATCH * SEQ * FFDIM * 2);

  // one-time per call: weight convert+transpose, input concat
  wconv_kernel<<<dim3(12, 12, 4), 256, 0, stream>>>(Wk, WkvT, HID, HID, 0, 1536);
  wconv_kernel<<<dim3(12, 12, 4), 256, 0, stream>>>(Wv, WkvT, HID, HID, 768, 1536);
  wconv_kernel<<<dim3(12, 12, 4), 256, 0, stream>>>(Wq, Wq1wT, HID, HID, 0, 1536);
  wconv_kernel<<<dim3(12, 12, 4), 256, 0, stream>>>(Wq_w2e, Wq1wT, HID, HID, 768, 1536);
  wconv_kernel<<<dim3(12, 12, 4), 256, 0, stream>>>(Wq_e2w, Wq1eT, HID, HID, 0, 1536);
  wconv_kernel<<<dim3(12, 12, 4), 256, 0, stream>>>(Wq_e2e, Wq1eT, HID, HID, 768, 1536);
  wconv_kernel<<<dim3(12, 12, 4), 256, 0, stream>>>(Wo, WoT, HID, HID, 0, 768);
  wconv_kernel<<<dim3(48, 12, 4), 256, 0, stream>>>(Wi, WiT, HID, FFDIM, 0, 3072);
  wconv_kernel<<<dim3(12, 48, 4), 256, 0, stream>>>(Wo2, Wo2T, FFDIM, HID, 0, 768);
  concat_kernel<<<6528, 256, 0, stream>>>(wh, ehs, h0f, hb);

  for (int l = 0; l < NLAYER; l++) {
    const float* hf = (l == 0) ? h0f : (out + (size_t)(l - 1) * BSH);
    // K|V (N=1536), bf16 out, 24x17=408 blocks
    gemm_bf16<<<dim3(24, 17, 1), 256, 0, stream>>>(hb, HID, 0,
        WkvT + (size_t)l * 1536 * HID, bk + l * HID, bv + l * HID, HID,
        nullptr, KVb, 1536, 0, NBATCH * SEQ, 1536, HID, 1, 1);
    // Q1|Q2 for word rows (batched z), 24x8x2=384 blocks
    gemm_bf16<<<dim3(24, 8, 2), 256, 0, stream>>>(hb, HID, (long)SEQ * HID,
        Wq1wT + (size_t)l * 1536 * HID, bq + l * HID, bq_w2e + l * HID, HID,
        nullptr, Q12, 1536, (long)SEQ * 1536, LWORD, 1536, HID, 1, 1);
    // Q1|Q2 for entity rows (batched z)
    gemm_bf16<<<dim3(24, 1, 2), 256, 0, stream>>>(hb + (size_t)LWORD * HID, HID, (long)SEQ * HID,
        Wq1eT + (size_t)l * 1536 * HID, bq_e2w + l * HID, bq_e2e + l * HID, HID,
        nullptr, Q12 + (size_t)LWORD * 1536, 1536, (long)SEQ * 1536, LENT, 1536, HID, 1, 1);
    vtrans_kernel<<<dim3(17, 12, 2), 256, 0, stream>>>(KVb, Vt);
    attn_kernel<<<dim3(17, 12, 2), 256, 0, stream>>>(KVb, Q12, Vt, mask, ctxb);
    // O projection: split-K x2 (fp32 partials), 12x17x2=408 blocks
    gemm_bf16<<<dim3(12, 17, 2), 256, 0, stream>>>(ctxb, HID, 0,
        WoT + (size_t)l * HID * HID, bo + l * HID, bo + l * HID, HID,
        tmpf, nullptr, HID, (long)BSH, NBATCH * SEQ, HID, HID, 0, 2);
    ln_kernel<<<NBATCH * SEQ, 256, 0, stream>>>(tmpf, tmpf + BSH, hf,
        g1 + l * HID, b1 + l * HID, attnf, attnb);
    // FFN up + exact GELU (bf16 out), 48x17=816 blocks
    gemm_bf16<<<dim3(48, 17, 1), 256, 0, stream>>>(attnb, HID, 0,
        WiT + (size_t)l * FFDIM * HID, bi + l * FFDIM, bi + l * FFDIM, FFDIM,
        nullptr, interb, FFDIM, 0, NBATCH * SEQ, FFDIM, HID, 2, 1);
    // FFN down: split-K x2 (fp32 partials), 12x17x2=408 blocks
    gemm_bf16<<<dim3(12, 17, 2), 256, 0, stream>>>(interb, FFDIM, 0,
        Wo2T + (size_t)l * HID * FFDIM, bo2 + l * HID, bo2 + l * HID, HID,
        tmpf, nullptr, HID, (long)BSH, NBATCH * SEQ, HID, FFDIM, 0, 2);
    ln_kernel<<<NBATCH * SEQ, 256, 0, stream>>>(tmpf, tmpf + BSH, attnf,
        g2 + l * HID, b2 + l * HID, out + (size_t)l * BSH, hb);
  }
}

// Round 4
// 1062.613 us; speedup vs baseline: 1.9036x; 1.7131x over previous
//
#include <hip/hip_runtime.h>
#include <hip/hip_bf16.h>
#include <math.h>

#define NLAYER 4
#define NBATCH 2
#define LWORD 1024
#define LENT 64
#define SEQ 1088
#define HID 768
#define NHEAD 12
#define DHEAD 64
#define FFDIM 3072

typedef __bf16 bf16_t;
typedef __bf16 bf16x8 __attribute__((ext_vector_type(8)));
typedef float f32x4 __attribute__((ext_vector_type(4)));

__device__ __forceinline__ bf16_t f2bf(float x) { return (bf16_t)x; }

// swizzle for 128B rows (8 x 16B chunks): involution c ^= (r&7)
#define SWZ8(r, c) ((((c) ^ ((r) & 7)) & 7) << 4)

// async global->LDS, 16B per lane; LDS dest = uniform base + lane*16 (linear)
__device__ __forceinline__ void gl16(const void* g, void* l) {
  __builtin_amdgcn_global_load_lds(
      (const __attribute__((address_space(1))) uint32_t*)g,
      (__attribute__((address_space(3))) uint32_t*)l, 16, 0, 0);
}

// ---------- weight transpose + convert: dst[l][roff+n][k] = src[l][k][n] ----------
__global__ __launch_bounds__(256) void wconv_kernel(
    const float* __restrict__ src, bf16_t* __restrict__ dst,
    int K, int N, int roff, int Rtot)
{
  int n0 = blockIdx.x * 64, k0 = blockIdx.y * 64, l = blockIdx.z;
  src += (size_t)l * K * N;
  dst += (size_t)l * Rtot * K;
  __shared__ float tile[64][65];
  int tid = threadIdx.x;
#pragma unroll
  for (int j = 0; j < 16; j++) {
    int e = j * 256 + tid;
    int rr = e >> 6, cc = e & 63;
    tile[rr][cc] = src[(size_t)(k0 + rr) * N + n0 + cc];
  }
  __syncthreads();
#pragma unroll
  for (int j = 0; j < 16; j++) {
    int e = j * 256 + tid;
    int rr = e >> 6, cc = e & 63; // rr = n index, cc = k index
    dst[(size_t)(roff + n0 + rr) * K + k0 + cc] = f2bf(tile[cc][rr]);
  }
}

// ---------- concat word+entity -> h (fp32 + bf16) ----------
__global__ __launch_bounds__(256) void concat_kernel(
    const float* __restrict__ wh, const float* __restrict__ eh,
    float* __restrict__ hf, bf16_t* __restrict__ hb)
{
  size_t i = (size_t)blockIdx.x * 256 + threadIdx.x;
  if (i >= (size_t)NBATCH * SEQ * HID) return;
  int c = (int)(i % HID);
  size_t t = i / HID;
  int s = (int)(t % SEQ);
  int b = (int)(t / SEQ);
  float v = (s < LWORD) ? wh[((size_t)b * LWORD + s) * HID + c]
                        : eh[((size_t)b * LENT + (s - LWORD)) * HID + c];
  hf[i] = v;
  hb[i] = f2bf(v);
}

// ---------- multi-job pipelined MFMA GEMM ----------
// block tile 128(M) x 64(N), BK=64, 4 waves (2x2), per-wave 64x32
// double-buffered LDS, global_load_lds staging, 1 barrier / K-step
// mode 0: fp32+bias; 1: bf16+bias; 2: gelu bf16+bias; 3: fp32 no bias (split-K tail)
struct Job {
  const bf16_t* A; const bf16_t* W; const float* b0; const float* b1; void* C;
  int M, ldaE, ldwE, ldcE, nbx, nsplit, kb, kn, mode;
};
struct JobPack { Job j[5]; int cum[5]; int njobs; };

__global__ __launch_bounds__(256) void gemm_mf(JobPack P)
{
  const int tid = threadIdx.x, lane = tid & 63, wid = tid >> 6;
  const int wm = wid >> 1, wn = wid & 1;
  const int g = lane >> 4, qq = lane & 15;
  const int lhi = lane >> 3, llo = lane & 7;

  // XCD-aware bijective swizzle (grid always %8==0 here)
  int bid0 = blockIdx.x, nwg = gridDim.x;
  int bid = ((nwg & 7) == 0) ? ((bid0 & 7) * (nwg >> 3) + (bid0 >> 3)) : bid0;

  int ji = 0;
  while (bid >= P.cum[ji]) ji++;
  const Job& J = P.j[ji];
  int local = bid - (ji ? P.cum[ji - 1] : 0);
  const int by = local / J.nbx, bx = local - by * J.nbx;
  const int m0 = by * 128, n0 = bx * 64;
  const int M = J.M, ldaE = J.ldaE, ldwE = J.ldwE, kb = J.kb;

  __shared__ char As[32768];   // 2 x 128 x 128B
  __shared__ char Bs[16384];   // 2 x  64 x 128B

  f32x4 acc[4][2] = {};

  auto stage = [&](int buf, int kOff) {
#pragma unroll
    for (int j = 0; j < 4; j++) {
      int r = wid * 32 + j * 8 + lhi;
      int rr = m0 + r; rr = (rr < M) ? rr : (M - 1);
      int cg = llo ^ (r & 7);
      const char* gp = (const char*)J.A + ((size_t)rr * ldaE + kb + kOff) * 2 + cg * 16;
      gl16(gp, As + buf * 16384 + (wid * 32 + j * 8) * 128);
    }
#pragma unroll
    for (int j = 0; j < 2; j++) {
      int r = wid * 16 + j * 8 + lhi;
      int cg = llo ^ (r & 7);
      const char* gp = (const char*)J.W + ((size_t)(n0 + r) * ldwE + kb + kOff) * 2 + cg * 16;
      gl16(gp, Bs + buf * 8192 + (wid * 16 + j * 8) * 128);
    }
  };
  auto comp = [&](int buf) {
#pragma unroll
    for (int kk = 0; kk < 2; kk++) {
      bf16x8 af[4], bfr[2];
      int c = kk * 4 + g;
#pragma unroll
      for (int mi = 0; mi < 4; mi++) {
        int r = wm * 64 + mi * 16 + qq;
        af[mi] = *(const bf16x8*)(As + buf * 16384 + r * 128 + SWZ8(r, c));
      }
#pragma unroll
      for (int ni = 0; ni < 2; ni++) {
        int r = wn * 32 + ni * 16 + qq;
        bfr[ni] = *(const bf16x8*)(Bs + buf * 8192 + r * 128 + SWZ8(r, c));
      }
#pragma unroll
      for (int mi = 0; mi < 4; mi++)
#pragma unroll
        for (int ni = 0; ni < 2; ni++)
          acc[mi][ni] = __builtin_amdgcn_mfma_f32_16x16x32_bf16(af[mi], bfr[ni], acc[mi][ni], 0, 0, 0);
    }
  };

  const int nT = J.kn >> 6;
  stage(0, 0);
  int cur = 0;
  for (int t = 0; t < nT; t++) {
    __syncthreads();                       // drains stage(t) [vmcnt in barrier]
    if (t + 1 < nT) stage(cur ^ 1, (t + 1) << 6);  // flies under compute(t)
    comp(cur);
    cur ^= 1;
  }

  const int mode = J.mode, ldcE = J.ldcE;
  float* Cf = (float*)J.C;
  bf16_t* Cb = (bf16_t*)J.C;
#pragma unroll
  for (int mi = 0; mi < 4; mi++) {
#pragma unroll
    for (int ni = 0; ni < 2; ni++) {
      int col = n0 + wn * 32 + ni * 16 + qq;
      float bv = (mode == 3) ? 0.f
               : ((col < J.nsplit) ? J.b0[col] : J.b1[col - J.nsplit]);
#pragma unroll
      for (int e = 0; e < 4; e++) {
        int r = m0 + wm * 64 + mi * 16 + g * 4 + e;
        if (r < M) {
          float x = acc[mi][ni][e] + bv;
          size_t off = (size_t)r * ldcE + col;
          if (mode == 1) Cb[off] = f2bf(x);
          else if (mode == 2) {
            float xg = 0.5f * x * (1.0f + erff(x * 0.70710678118654752f));
            Cb[off] = f2bf(xg);
          } else Cf[off] = x;
        }
      }
    }
  }
}

// ---------- transpose V (from KV cols 768..1535) -> Vt (B,NH,DH,SEQ) ----------
__global__ __launch_bounds__(256) void vtrans_kernel(
    const bf16_t* __restrict__ KV, bf16_t* __restrict__ Vt)
{
  int kt = blockIdx.x, head = blockIdx.y, b = blockIdx.z;
  __shared__ bf16_t tile[64][65];
  int tid = threadIdx.x;
#pragma unroll
  for (int j = 0; j < 16; j++) {
    int e = j * 256 + tid;
    int rr = e >> 6, cc = e & 63; // rr = key, cc = dh
    tile[rr][cc] = KV[((size_t)(b * SEQ + kt * 64 + rr)) * 1536 + 768 + head * 64 + cc];
  }
  __syncthreads();
#pragma unroll
  for (int j = 0; j < 16; j++) {
    int e = j * 256 + tid;
    int rr = e >> 6, cc = e & 63; // rr = dh, cc = key
    Vt[(((size_t)(b * NHEAD + head)) * 64 + rr) * SEQ + kt * 64 + cc] = tile[cc][rr];
  }
}

// ---------- flash attention ----------
__global__ __launch_bounds__(256) void attn_kernel(
    const bf16_t* __restrict__ KV, const bf16_t* __restrict__ Q12,
    const bf16_t* __restrict__ Vt, const float* __restrict__ mask,
    bf16_t* __restrict__ ctx)
{
  const int tid = threadIdx.x, lane = tid & 63, w = tid >> 6;
  const int qt = blockIdx.x, head = blockIdx.y, b = blockIdx.z;
  const int g = lane >> 4, qq = lane & 15;
  const int q0 = qt * 64 + w * 16;
  __shared__ char Ks[8192];
  __shared__ char Vs[8192];
  __shared__ bf16_t Pl[4][16][32];

  bf16x8 q1f[2], q2f[2];
  {
    const bf16_t* Qb = Q12 + ((size_t)(b * SEQ + q0 + qq)) * 1536 + head * 64;
#pragma unroll
    for (int kk = 0; kk < 2; kk++) {
      q1f[kk] = *(const bf16x8*)(Qb + kk * 32 + g * 8);
      q2f[kk] = *(const bf16x8*)(Qb + 768 + kk * 32 + g * 8);
    }
  }

  f32x4 oacc[4] = {};
  float mrun[4] = {-INFINITY, -INFINITY, -INFINITY, -INFINITY};
  float lrun[4] = {0.f, 0.f, 0.f, 0.f};

  for (int t = 0; t < SEQ / 64; t++) {
    int key0 = t * 64;
    __syncthreads();
#pragma unroll
    for (int j = 0; j < 2; j++) {
      int o = j * 4096 + tid * 16;
      int r = o >> 7, c = (o >> 4) & 7;
      int sw = r * 128 + SWZ8(r, c);
      uint4 vk = *(const uint4*)(KV + (size_t)(b * SEQ + key0 + r) * 1536 + head * 64 + c * 8);
      *(uint4*)(Ks + sw) = vk;
      uint4 vv = *(const uint4*)(Vt + ((size_t)(b * NHEAD + head) * 64 + r) * SEQ + key0 + c * 8);
      *(uint4*)(Vs + sw) = vv;
    }
    __syncthreads();
    const bool useQ2 = (key0 >= LWORD);
#pragma unroll
    for (int ch = 0; ch < 2; ch++) {
      f32x4 s0 = {}, s1 = {};
#pragma unroll
      for (int kk = 0; kk < 2; kk++) {
        int r0 = ch * 32 + qq, r1 = r0 + 16;
        int c = kk * 4 + g;
        bf16x8 kf0 = *(const bf16x8*)(Ks + r0 * 128 + SWZ8(r0, c));
        bf16x8 kf1 = *(const bf16x8*)(Ks + r1 * 128 + SWZ8(r1, c));
        bf16x8 qf = useQ2 ? q2f[kk] : q1f[kk];
        s0 = __builtin_amdgcn_mfma_f32_16x16x32_bf16(qf, kf0, s0, 0, 0, 0);
        s1 = __builtin_amdgcn_mfma_f32_16x16x32_bf16(qf, kf1, s1, 0, 0, 0);
      }
      float mk0 = mask[b * SEQ + key0 + ch * 32 + qq];
      float mk1 = mask[b * SEQ + key0 + ch * 32 + 16 + qq];
      f32x4 mx;
#pragma unroll
      for (int e = 0; e < 4; e++) {
        s0[e] = s0[e] * 0.125f + mk0;
        s1[e] = s1[e] * 0.125f + mk1;
        mx[e] = fmaxf(s0[e], s1[e]);
      }
#pragma unroll
      for (int d = 1; d < 16; d <<= 1)
#pragma unroll
        for (int e = 0; e < 4; e++) mx[e] = fmaxf(mx[e], __shfl_xor(mx[e], d));
      float corr[4];
#pragma unroll
      for (int e = 0; e < 4; e++) {
        float mnew = fmaxf(mrun[e], mx[e]);
        corr[e] = __expf(mrun[e] - mnew);
        mrun[e] = mnew;
        lrun[e] *= corr[e];
      }
#pragma unroll
      for (int f = 0; f < 4; f++)
#pragma unroll
        for (int e = 0; e < 4; e++) oacc[f][e] *= corr[e];
      f32x4 p0, p1, rs;
#pragma unroll
      for (int e = 0; e < 4; e++) {
        p0[e] = __expf(s0[e] - mrun[e]);
        p1[e] = __expf(s1[e] - mrun[e]);
        rs[e] = p0[e] + p1[e];
      }
#pragma unroll
      for (int d = 1; d < 16; d <<= 1)
#pragma unroll
        for (int e = 0; e < 4; e++) rs[e] += __shfl_xor(rs[e], d);
#pragma unroll
      for (int e = 0; e < 4; e++) {
        lrun[e] += rs[e];
        Pl[w][g * 4 + e][qq] = f2bf(p0[e]);
        Pl[w][g * 4 + e][16 + qq] = f2bf(p1[e]);
      }
      bf16x8 pf = *(const bf16x8*)(&Pl[w][qq][g * 8]);
#pragma unroll
      for (int f = 0; f < 4; f++) {
        int r = f * 16 + qq;
        int c = ch * 4 + g;
        bf16x8 vf = *(const bf16x8*)(Vs + r * 128 + SWZ8(r, c));
        oacc[f] = __builtin_amdgcn_mfma_f32_16x16x32_bf16(pf, vf, oacc[f], 0, 0, 0);
      }
    }
  }
#pragma unroll
  for (int f = 0; f < 4; f++)
#pragma unroll
    for (int e = 0; e < 4; e++) {
      float val = oacc[f][e] / lrun[e];
      int row = q0 + g * 4 + e;
      ctx[((size_t)(b * SEQ) + row) * HID + head * 64 + f * 16 + qq] = f2bf(val);
    }
}

// ---------- residual + sum of nplanes split-K partials + LayerNorm ----------
__global__ __launch_bounds__(256) void ln_kernel(
    const float* __restrict__ X, long planeStride, int nplanes,
    const float* __restrict__ R,
    const float* __restrict__ gamma, const float* __restrict__ beta,
    float* __restrict__ outF, bf16_t* __restrict__ outB)
{
  int row = blockIdx.x;
  const float* x = X + (size_t)row * HID;
  const float* r = R + (size_t)row * HID;
  int tid = threadIdx.x;
  float v[3];
  float s = 0.f, ss = 0.f;
#pragma unroll
  for (int j = 0; j < 3; j++) {
    int c = tid + j * 256;
    float t = r[c];
    for (int p = 0; p < nplanes; p++) t += x[c + (size_t)p * planeStride];
    v[j] = t; s += t; ss += t * t;
  }
#pragma unroll
  for (int d = 1; d < 64; d <<= 1) { s += __shfl_xor(s, d); ss += __shfl_xor(ss, d); }
  __shared__ float red[8];
  int wid = tid >> 6, lane = tid & 63;
  if (lane == 0) { red[wid] = s; red[4 + wid] = ss; }
  __syncthreads();
  s = red[0] + red[1] + red[2] + red[3];
  ss = red[4] + red[5] + red[6] + red[7];
  float mean = s * (1.0f / HID);
  float var = ss * (1.0f / HID) - mean * mean;
  float inv = rsqrtf(var + 1e-12f);
#pragma unroll
  for (int j = 0; j < 3; j++) {
    int c = tid + j * 256;
    float y = (v[j] - mean) * inv * gamma[c] + beta[c];
    outF[(size_t)row * HID + c] = y;
    outB[(size_t)row * HID + c] = f2bf(y);
  }
}

extern "C" void kernel_launch(void* const* d_in, const int* in_sizes, int n_in,
                              void* d_out, int out_size, void* d_ws, size_t ws_size,
                              hipStream_t stream) {
  (void)in_sizes; (void)n_in; (void)out_size; (void)ws_size;
  const float* wh     = (const float*)d_in[0];
  const float* ehs    = (const float*)d_in[1];
  const float* mask   = (const float*)d_in[2];
  const float* Wq     = (const float*)d_in[3];  const float* bq     = (const float*)d_in[4];
  const float* Wk     = (const float*)d_in[5];  const float* bk     = (const float*)d_in[6];
  const float* Wv     = (const float*)d_in[7];  const float* bv     = (const float*)d_in[8];
  const float* Wq_w2e = (const float*)d_in[9];  const float* bq_w2e = (const float*)d_in[10];
  const float* Wq_e2w = (const float*)d_in[11]; const float* bq_e2w = (const float*)d_in[12];
  const float* Wq_e2e = (const float*)d_in[13]; const float* bq_e2e = (const float*)d_in[14];
  const float* Wo     = (const float*)d_in[15]; const float* bo     = (const float*)d_in[16];
  const float* Wi     = (const float*)d_in[17]; const float* bi     = (const float*)d_in[18];
  const float* Wo2    = (const float*)d_in[19]; const float* bo2    = (const float*)d_in[20];
  const float* g1     = (const float*)d_in[21]; const float* b1     = (const float*)d_in[22];
  const float* g2     = (const float*)d_in[23]; const float* b2     = (const float*)d_in[24];
  float* out = (float*)d_out;

  const size_t BSH = (size_t)NBATCH * SEQ * HID;
  char* ws = (char*)d_ws;
  size_t off = 0;
  auto alloc = [&](size_t bytes) -> char* {
    char* p = ws + off; off += (bytes + 255) & ~(size_t)255; return p;
  };
  bf16_t* WkvT  = (bf16_t*)alloc((size_t)NLAYER * 1536 * HID * 2);
  bf16_t* Wq1wT = (bf16_t*)alloc((size_t)NLAYER * 1536 * HID * 2);
  bf16_t* Wq1eT = (bf16_t*)alloc((size_t)NLAYER * 1536 * HID * 2);
  bf16_t* WoT   = (bf16_t*)alloc((size_t)NLAYER * HID * HID * 2);
  bf16_t* WiT   = (bf16_t*)alloc((size_t)NLAYER * FFDIM * HID * 2);
  bf16_t* Wo2T  = (bf16_t*)alloc((size_t)NLAYER * HID * FFDIM * 2);
  float*  h0f   = (float*) alloc(BSH * 4);
  bf16_t* hb    = (bf16_t*)alloc(BSH * 2);
  bf16_t* KVb   = (bf16_t*)alloc((size_t)NBATCH * SEQ * 1536 * 2);
  bf16_t* Q12   = (bf16_t*)alloc((size_t)NBATCH * SEQ * 1536 * 2);
  bf16_t* Vt    = (bf16_t*)alloc((size_t)NBATCH * NHEAD * DHEAD * SEQ * 2);
  bf16_t* ctxb  = (bf16_t*)alloc(BSH * 2);
  float*  tmpf  = (float*) alloc(BSH * 4 * 4);   // 4 split-K partial planes
  float*  attnf = (float*) alloc(BSH * 4);
  bf16_t* attnb = (bf16_t*)alloc(BSH * 2);
  bf16_t* interb= (bf16_t*)alloc((size_t)NBATCH * SEQ * FFDIM * 2);

  // one-time per call: weight convert+transpose, input concat
  wconv_kernel<<<dim3(12, 12, 4), 256, 0, stream>>>(Wk, WkvT, HID, HID, 0, 1536);
  wconv_kernel<<<dim3(12, 12, 4), 256, 0, stream>>>(Wv, WkvT, HID, HID, 768, 1536);
  wconv_kernel<<<dim3(12, 12, 4), 256, 0, stream>>>(Wq, Wq1wT, HID, HID, 0, 1536);
  wconv_kernel<<<dim3(12, 12, 4), 256, 0, stream>>>(Wq_w2e, Wq1wT, HID, HID, 768, 1536);
  wconv_kernel<<<dim3(12, 12, 4), 256, 0, stream>>>(Wq_e2w, Wq1eT, HID, HID, 0, 1536);
  wconv_kernel<<<dim3(12, 12, 4), 256, 0, stream>>>(Wq_e2e, Wq1eT, HID, HID, 768, 1536);
  wconv_kernel<<<dim3(12, 12, 4), 256, 0, stream>>>(Wo, WoT, HID, HID, 0, 768);
  wconv_kernel<<<dim3(48, 12, 4), 256, 0, stream>>>(Wi, WiT, HID, FFDIM, 0, 3072);
  wconv_kernel<<<dim3(12, 48, 4), 256, 0, stream>>>(Wo2, Wo2T, FFDIM, HID, 0, 768);
  concat_kernel<<<6528, 256, 0, stream>>>(wh, ehs, h0f, hb);

  auto mkjob = [](const bf16_t* A, const bf16_t* W, const float* pb0, const float* pb1,
                  void* C, int M, int ldaE, int ldwE, int ldcE, int nbx, int nsplit,
                  int kb, int kn, int mode) -> Job {
    Job j; j.A = A; j.W = W; j.b0 = pb0; j.b1 = pb1; j.C = C; j.M = M;
    j.ldaE = ldaE; j.ldwE = ldwE; j.ldcE = ldcE; j.nbx = nbx; j.nsplit = nsplit;
    j.kb = kb; j.kn = kn; j.mode = mode; return j;
  };
  auto pack = [](Job* js, int n, int* nblk) -> JobPack {
    JobPack P{}; int c = 0;
    for (int i = 0; i < n; i++) { P.j[i] = js[i]; c += nblk[i]; P.cum[i] = c; }
    for (int i = n; i < 5; i++) P.cum[i] = c;
    P.njobs = n; return P;
  };

  for (int l = 0; l < NLAYER; l++) {
    const float* hf = (l == 0) ? h0f : (out + (size_t)(l - 1) * BSH);

    // ---- phase A: KV (full) + Qword(b0,b1) + Qent(b0,b1), 840 blocks ----
    {
      Job js[5]; int nb[5];
      js[0] = mkjob(hb, WkvT + (size_t)l * 1536 * HID, bk + l * HID, bv + l * HID,
                    KVb, NBATCH * SEQ, HID, HID, 1536, 24, HID, 0, HID, 1);
      nb[0] = 24 * 17;
      for (int b = 0; b < 2; b++) {
        js[1 + b] = mkjob(hb + (size_t)b * SEQ * HID,
                          Wq1wT + (size_t)l * 1536 * HID, bq + l * HID, bq_w2e + l * HID,
                          Q12 + (size_t)b * SEQ * 1536, LWORD, HID, HID, 1536, 24, HID, 0, HID, 1);
        nb[1 + b] = 24 * 8;
        js[3 + b] = mkjob(hb + ((size_t)b * SEQ + LWORD) * HID,
                          Wq1eT + (size_t)l * 1536 * HID, bq_e2w + l * HID, bq_e2e + l * HID,
                          Q12 + ((size_t)b * SEQ + LWORD) * 1536, LENT, HID, HID, 1536, 24, HID, 0, HID, 1);
        nb[3 + b] = 24 * 1;
      }
      JobPack P = pack(js, 5, nb);
      gemm_mf<<<840, 256, 0, stream>>>(P);
    }

    vtrans_kernel<<<dim3(17, 12, 2), 256, 0, stream>>>(KVb, Vt);
    attn_kernel<<<dim3(17, 12, 2), 256, 0, stream>>>(KVb, Q12, Vt, mask, ctxb);

    // ---- phase B: O-projection, split-K x4 (kn=192), 816 blocks ----
    {
      Job js[4]; int nb[4];
      for (int z = 0; z < 4; z++) {
        js[z] = mkjob(ctxb, WoT + (size_t)l * HID * HID, bo + l * HID, bo + l * HID,
                      tmpf + (size_t)z * BSH, NBATCH * SEQ, HID, HID, HID, 12, HID,
                      z * 192, 192, z ? 3 : 0);
        nb[z] = 12 * 17;
      }
      JobPack P = pack(js, 4, nb);
      gemm_mf<<<816, 256, 0, stream>>>(P);
    }
    ln_kernel<<<NBATCH * SEQ, 256, 0, stream>>>(tmpf, (long)BSH, 4, hf,
        g1 + l * HID, b1 + l * HID, attnf, attnb);

    // ---- phase C: FFN up + GELU, 816 blocks ----
    {
      Job js[1]; int nb[1];
      js[0] = mkjob(attnb, WiT + (size_t)l * FFDIM * HID, bi + l * FFDIM, bi + l * FFDIM,
                    interb, NBATCH * SEQ, HID, HID, FFDIM, 48, FFDIM, 0, HID, 2);
      nb[0] = 48 * 17;
      JobPack P = pack(js, 1, nb);
      gemm_mf<<<816, 256, 0, stream>>>(P);
    }

    // ---- phase D: FFN down, split-K x4 (kn=768), 816 blocks ----
    {
      Job js[4]; int nb[4];
      for (int z = 0; z < 4; z++) {
        js[z] = mkjob(interb, Wo2T + (size_t)l * HID * FFDIM, bo2 + l * HID, bo2 + l * HID,
                      tmpf + (size_t)z * BSH, NBATCH * SEQ, FFDIM, FFDIM, HID, 12, HID,
                      z * 768, 768, z ? 3 : 0);
        nb[z] = 12 * 17;
      }
      JobPack P = pack(js, 4, nb);
      gemm_mf<<<816, 256, 0, stream>>>(P);
    }
    ln_kernel<<<NBATCH * SEQ, 256, 0, stream>>>(tmpf, (long)BSH, 4, attnf,
        g2 + l * HID, b2 + l * HID, out + (size_t)l * BSH, hb);
  }
}